// Round 14
// baseline (105.369 us; speedup 1.0000x reference)
//
#include <hip/hip_runtime.h>
#include <hip/hip_bf16.h>

typedef float f32x4 __attribute__((ext_vector_type(4)));

#define NB 32      // batch
#define NT 2000    // time
#define NW 512     // width
#define NG 20      // groups (T / NUM_STEPS)
#define NS 100     // NUM_STEPS
#define NH 1024    // hidden
#define NO 10      // outputs
#define BETA 0.95f
#define THRESH 1.0f

// ------- Kernel 1 (fused): conv+scan1 blocks [0,1280) + transpose blocks [1280,1792) -------
// k1 part: ROUND-3 VERSION, marginal-measured ~78us (round 5) = HBM roofline. FROZEN.
__global__ __launch_bounds__(256) void k1_conv_scan_tr(
    const f32x4* __restrict__ x,    // [B][T][W] of float4 (C=4 innermost)
    const float* __restrict__ cw,   // [4]
    const float* __restrict__ cb,   // [1]
    float* __restrict__ spk1,       // [B][G][W]
    const float* __restrict__ wsrc, // [H][W] hidden_w
    float* __restrict__ wT)         // [W][H]
{
    __shared__ float tile[32][33];
    int bid = blockIdx.x;

    if (bid < 1280) {
        int half = bid & 1;             // which half of the 512-wide row
        int bg = bid >> 1;              // 0..639
        int g = bg % NG;
        int b = bg / NG;
        int tid = threadIdx.x;          // 0..255

        const f32x4* __restrict__ base =
            x + ((size_t)(b * NT + g * NS) * NW + half * 256);

        float w0 = cw[0], w1 = cw[1], w2 = cw[2], w3 = cw[3];
        float bias = cb[0];

        f32x4 A[10], B[10];
        float mem = 0.0f;

#define LOAD10(dst, S0)                                                        \
    {                                                                          \
        _Pragma("unroll")                                                      \
        for (int j = 0; j < 10; ++j)                                           \
            dst[j] = __builtin_nontemporal_load(base + (tid + ((S0) + j) * NW)); \
    }
#define STEP10(src)                                                            \
    {                                                                          \
        _Pragma("unroll")                                                      \
        for (int j = 0; j < 10; ++j) {                                         \
            f32x4 v = src[j];                                                  \
            float f = fmaf(v[0], w0, fmaf(v[1], w1,                            \
                      fmaf(v[2], w2, fmaf(v[3], w3, bias))));                  \
            float base_m = fmaf(BETA, mem, f);                                 \
            mem = (mem > THRESH) ? 0.0f : base_m;                              \
        }                                                                      \
    }

        LOAD10(A, 0)
        LOAD10(B, 10) STEP10(A)
        LOAD10(A, 20) STEP10(B)
        LOAD10(B, 30) STEP10(A)
        LOAD10(A, 40) STEP10(B)
        LOAD10(B, 50) STEP10(A)
        LOAD10(A, 60) STEP10(B)
        LOAD10(B, 70) STEP10(A)
        LOAD10(A, 80) STEP10(B)
        LOAD10(B, 90) STEP10(A)
        STEP10(B)
#undef LOAD10
#undef STEP10

        spk1[(b * NG + g) * NW + half * 256 + tid] = (mem > THRESH) ? 1.0f : 0.0f;
    } else {
        // transpose hidden_w (1024x512 -> 512x1024)
        int tbid = bid - 1280;           // 0..511
        int bk = tbid & 15;              // 16 tiles over W
        int bh = tbid >> 4;              // 32 tiles over H
        int tx = threadIdx.x & 31;       // 0..31
        int ty = threadIdx.x >> 5;       // 0..7
        #pragma unroll
        for (int j = 0; j < 4; ++j)
            tile[ty + j * 8][tx] = wsrc[(bh * 32 + ty + j * 8) * NW + bk * 32 + tx];
        __syncthreads();
        #pragma unroll
        for (int j = 0; j < 4; ++j)
            wT[(bk * 32 + ty + j * 8) * NH + bh * 32 + tx] = tile[tx][ty + j * 8];
    }
}

// ---------------- Kernel 2 v7: hidden GEMM + scan2 + output-partials ------------
// Round-13 arithmetic: v5 issues 2560 broadcast ds_read_b128 per CU (~12.8us
// of LDS-pipe occupancy at ~12cy each) = the k2 residual. v7 halves it by
// combining the two PROVEN levers with affine addressing kept: 512-thread
// blocks (8 waves = 2/SIMD, same TLP as v5), h-QUAD per thread (16 k-chunks
// x 32 lanes), f32x4 wT loads (512B/32 lanes, affine). 2 sk addrs/wave are
// 128B apart = 2-way same-bank = free (m136). LDS 40KB: red[8][10][32] f32x4
// ALIASED onto dead sk; 16->8->4 tree; scan threads (t<128) carry mem across
// two g-half passes. Grid 256 = 1 block/CU exactly.
__global__ __launch_bounds__(512, 2) void k2_hidden_scan(
    const float* __restrict__ spk1,  // [B][G][W]
    const float* __restrict__ wT,    // [W][H]
    const float* __restrict__ hb,    // [H]
    const float* __restrict__ ow,    // [O][H]
    float* __restrict__ partial)     // [B][16][10]
{
    __shared__ __align__(16) char smem[40960];
    float (*sk)[NW] = (float (*)[NW])smem;            // [20][512] floats
    f32x4 (*red)[10][32] = (f32x4 (*)[10][32])smem;   // [8][10][32] f32x4 (aliased)

    int bid = blockIdx.x;            // 0..255
    int b = bid >> 3;                // 0..31
    int hgrp = bid & 7;              // 0..7 (128 h per block)
    int t = threadIdx.x;             // 0..511
    int lane5 = t & 31;
    int c = t >> 5;                  // k-chunk 0..15 (32 kk each)
    int h = hgrp * 128 + lane5 * 4;  // h-quad base

    // cooperative stage: 2560 float4 / 512 threads = 5 each, coalesced
    {
        const f32x4* __restrict__ sp4 =
            (const f32x4*)(spk1 + (size_t)b * NG * NW);
        f32x4* sk4 = (f32x4*)smem;
        #pragma unroll
        for (int i = 0; i < 5; ++i)
            sk4[t + i * 512] = sp4[t + i * 512];
    }
    __syncthreads();

    f32x4 acc[NG];
    #pragma unroll
    for (int g = 0; g < NG; ++g)
        #pragma unroll
        for (int j = 0; j < 4; ++j) acc[g][j] = 0.0f;

    int k0 = c * 32;
    #pragma unroll 2
    for (int kkg = 0; kkg < 8; ++kkg) {
        int kk = k0 + kkg * 4;
        f32x4 w0 = *(const f32x4*)&wT[(kk + 0) * NH + h];
        f32x4 w1 = *(const f32x4*)&wT[(kk + 1) * NH + h];
        f32x4 w2 = *(const f32x4*)&wT[(kk + 2) * NH + h];
        f32x4 w3 = *(const f32x4*)&wT[(kk + 3) * NH + h];
        #pragma unroll
        for (int g = 0; g < NG; ++g) {
            f32x4 u = *(const f32x4*)&sk[g][kk];   // 2 addrs/wave, 2-way = free
            #pragma unroll
            for (int j = 0; j < 4; ++j)
                acc[g][j] = fmaf(u[0], w0[j], fmaf(u[1], w1[j],
                            fmaf(u[2], w2[j], fmaf(u[3], w3[j], acc[g][j]))));
        }
    }

    // scan state lives in t<128 (these are also the c<4 writer threads)
    float hbias = 0.0f, mem = 0.0f;
    if (t < 128) hbias = hb[hgrp * 128 + t];
    int hl = t >> 2, hj = t & 3;

    // two g-half passes through the 40KB aliased reduction buffer
    #pragma unroll
    for (int pass = 0; pass < 2; ++pass) {
        __syncthreads();             // pass0: sk dead; pass1: prev red consumed
        if (c < 8) {
            #pragma unroll
            for (int gg = 0; gg < 10; ++gg)
                red[c][gg][lane5] = acc[pass * 10 + gg];
        }
        __syncthreads();
        if (c >= 8) {
            #pragma unroll
            for (int gg = 0; gg < 10; ++gg) {
                f32x4 v = red[c - 8][gg][lane5];
                f32x4 a = acc[pass * 10 + gg];
                #pragma unroll
                for (int j = 0; j < 4; ++j) v[j] += a[j];
                red[c - 8][gg][lane5] = v;
            }
        }
        __syncthreads();
        if (c >= 4 && c < 8) {
            #pragma unroll
            for (int gg = 0; gg < 10; ++gg) {
                f32x4 v = red[c - 4][gg][lane5];
                f32x4 a = red[c][gg][lane5];
                #pragma unroll
                for (int j = 0; j < 4; ++j) v[j] += a[j];
                red[c - 4][gg][lane5] = v;
            }
        }
        __syncthreads();
        if (t < 128) {
            #pragma unroll
            for (int gg = 0; gg < 10; ++gg) {
                float xin = red[0][gg][hl][hj] + red[1][gg][hl][hj]
                          + red[2][gg][hl][hj] + red[3][gg][hl][hj] + hbias;
                float base = fmaf(BETA, mem, xin);
                mem = (mem > THRESH) ? 0.0f : base;
            }
        }
    }

    // output dots: t<128 spans 2 waves -> two partial slots (hgrp*2, hgrp*2+1)
    if (t < 128) {
        float spike = (mem > THRESH) ? 1.0f : 0.0f;
        int slot = hgrp * 2 + (t >> 6);
        #pragma unroll
        for (int o = 0; o < NO; ++o) {
            float p = spike * ow[o * NH + hgrp * 128 + t];
            p += __shfl_down(p, 32);
            p += __shfl_down(p, 16);
            p += __shfl_down(p, 8);
            p += __shfl_down(p, 4);
            p += __shfl_down(p, 2);
            p += __shfl_down(p, 1);
            if ((t & 63) == 0) partial[(b * 16 + slot) * NO + o] = p;
        }
    }
}

// ---------------- Kernel 3: micro softmax over summed partials ----------------
__global__ __launch_bounds__(64) void k_softmax(
    const float* __restrict__ partial,  // [B][16][10]
    const float* __restrict__ ob,       // [10]
    float* __restrict__ out)            // [B][10]
{
    int t = threadIdx.x;
    if (t < NB) {
        const float* p = partial + t * 16 * NO;
        float v[NO];
        #pragma unroll
        for (int o = 0; o < NO; ++o) v[o] = ob[o];
        #pragma unroll
        for (int hg = 0; hg < 16; ++hg)
            #pragma unroll
            for (int o = 0; o < NO; ++o) v[o] += p[hg * NO + o];

        float mx = -1e30f;
        #pragma unroll
        for (int o = 0; o < NO; ++o) mx = fmaxf(mx, v[o]);
        float sum = 0.0f;
        #pragma unroll
        for (int o = 0; o < NO; ++o) { v[o] = expf(v[o] - mx); sum += v[o]; }
        float inv = 1.0f / sum;
        #pragma unroll
        for (int o = 0; o < NO; ++o) out[t * NO + o] = v[o] * inv;
    }
}

extern "C" void kernel_launch(void* const* d_in, const int* in_sizes, int n_in,
                              void* d_out, int out_size, void* d_ws, size_t ws_size,
                              hipStream_t stream) {
    const f32x4*  x  = (const f32x4*)d_in[0];   // [32][2000][512][4]
    const float*  cw = (const float*)d_in[1];   // [4]
    const float*  cb = (const float*)d_in[2];   // [1]
    const float*  hw = (const float*)d_in[3];   // [1024][512]
    const float*  hb = (const float*)d_in[4];   // [1024]
    const float*  ow = (const float*)d_in[5];   // [10][1024]
    const float*  ob = (const float*)d_in[6];   // [10]
    float* out = (float*)d_out;                 // [32][10]

    char* ws = (char*)d_ws;
    float* spk1    = (float*)(ws);                        // 32*20*512*4 = 1,310,720 B
    float* wT      = (float*)(ws + 1310720);              // 512*1024*4  = 2,097,152 B
    float* partial = (float*)(ws + 1310720 + 2097152);    // 32*16*10*4  =    20,480 B

    // stage 1: conv + scan1 (~78us, HBM roofline) fused with weight transpose
    k1_conv_scan_tr<<<1792, 256, 0, stream>>>(x, cw, cb, spk1, hw, wT);

    // stage 2+3+4a: hidden GEMM (h-quad, 512-thr, halved LDS issue) + scan2
    k2_hidden_scan<<<NB * 8, 512, 0, stream>>>(spk1, wT, hb, ow, partial);

    // stage 4b: sum partials + bias + softmax (1 tiny block)
    k_softmax<<<1, 64, 0, stream>>>(partial, ob, out);
}

// Round 15
// 103.544 us; speedup vs baseline: 1.0176x; 1.0176x over previous
//
#include <hip/hip_runtime.h>
#include <hip/hip_bf16.h>

typedef float f32x4 __attribute__((ext_vector_type(4)));

#define NB 32      // batch
#define NT 2000    // time
#define NW 512     // width
#define NG 20      // groups (T / NUM_STEPS)
#define NS 100     // NUM_STEPS
#define NH 1024    // hidden
#define NO 10      // outputs
#define BETA 0.95f
#define THRESH 1.0f

// ------- Kernel 1 (fused): conv+scan1 blocks [0,1280) + transpose blocks [1280,1792) -------
// k1 part: ROUND-3 VERSION, marginal-measured ~78us (round 5) = 6.7 TB/s effective,
// above the 6.29 TB/s empirical copy ceiling. FROZEN.
__global__ __launch_bounds__(256) void k1_conv_scan_tr(
    const f32x4* __restrict__ x,    // [B][T][W] of float4 (C=4 innermost)
    const float* __restrict__ cw,   // [4]
    const float* __restrict__ cb,   // [1]
    float* __restrict__ spk1,       // [B][G][W]
    const float* __restrict__ wsrc, // [H][W] hidden_w
    float* __restrict__ wT)         // [W][H]
{
    __shared__ float tile[32][33];
    int bid = blockIdx.x;

    if (bid < 1280) {
        int half = bid & 1;             // which half of the 512-wide row
        int bg = bid >> 1;              // 0..639
        int g = bg % NG;
        int b = bg / NG;
        int tid = threadIdx.x;          // 0..255

        const f32x4* __restrict__ base =
            x + ((size_t)(b * NT + g * NS) * NW + half * 256);

        float w0 = cw[0], w1 = cw[1], w2 = cw[2], w3 = cw[3];
        float bias = cb[0];

        f32x4 A[10], B[10];
        float mem = 0.0f;

#define LOAD10(dst, S0)                                                        \
    {                                                                          \
        _Pragma("unroll")                                                      \
        for (int j = 0; j < 10; ++j)                                           \
            dst[j] = __builtin_nontemporal_load(base + (tid + ((S0) + j) * NW)); \
    }
#define STEP10(src)                                                            \
    {                                                                          \
        _Pragma("unroll")                                                      \
        for (int j = 0; j < 10; ++j) {                                         \
            f32x4 v = src[j];                                                  \
            float f = fmaf(v[0], w0, fmaf(v[1], w1,                            \
                      fmaf(v[2], w2, fmaf(v[3], w3, bias))));                  \
            float base_m = fmaf(BETA, mem, f);                                 \
            mem = (mem > THRESH) ? 0.0f : base_m;                              \
        }                                                                      \
    }

        LOAD10(A, 0)
        LOAD10(B, 10) STEP10(A)
        LOAD10(A, 20) STEP10(B)
        LOAD10(B, 30) STEP10(A)
        LOAD10(A, 40) STEP10(B)
        LOAD10(B, 50) STEP10(A)
        LOAD10(A, 60) STEP10(B)
        LOAD10(B, 70) STEP10(A)
        LOAD10(A, 80) STEP10(B)
        LOAD10(B, 90) STEP10(A)
        STEP10(B)
#undef LOAD10
#undef STEP10

        spk1[(b * NG + g) * NW + half * 256 + tid] = (mem > THRESH) ? 1.0f : 0.0f;
    } else {
        // transpose hidden_w (1024x512 -> 512x1024)
        int tbid = bid - 1280;           // 0..511
        int bk = tbid & 15;              // 16 tiles over W
        int bh = tbid >> 4;              // 32 tiles over H
        int tx = threadIdx.x & 31;       // 0..31
        int ty = threadIdx.x >> 5;       // 0..7
        #pragma unroll
        for (int j = 0; j < 4; ++j)
            tile[ty + j * 8][tx] = wsrc[(bh * 32 + ty + j * 8) * NW + bk * 32 + tx];
        __syncthreads();
        #pragma unroll
        for (int j = 0; j < 4; ++j)
            wT[(bk * 32 + ty + j * 8) * NH + bh * 32 + tx] = tile[tx][ty + j * 8];
    }
}

// ---------------- Kernel 2 v5: hidden GEMM + scan2 + output-partials ------------
// ROUND-10 VERSION VERBATIM (proven best: 103.6 total). 512 blocks (2/CU),
// h-pair float2 acc, 8 k-chunks (c=t>>5, half-wave-uniform sk broadcasts),
// LDS 60 KB (sk 40 + red 20).
__global__ __launch_bounds__(256) void k2_hidden_scan(
    const float* __restrict__ spk1,  // [B][G][W]
    const float* __restrict__ wT,    // [W][H]
    const float* __restrict__ hb,    // [H]
    const float* __restrict__ ow,    // [O][H]
    float* __restrict__ partial)     // [B][16][10]
{
    __shared__ float sk[NG][NW];     // 40 KB: spk1[b] slice
    __shared__ float red[4][NG][64]; // 20 KB: reduction buffer

    int bid = blockIdx.x;            // 0..511
    int b = bid >> 4;                // 0..31
    int hgrp = bid & 15;             // 0..15 (64 h per block)
    int t = threadIdx.x;
    int lane5 = t & 31;
    int c = t >> 5;                  // k-chunk 0..7 (64 kk each)
    int h = hgrp * 64 + lane5 * 2;   // h-pair base

    // cooperative stage: 2560 float4 / 256 threads = 10 each, coalesced
    {
        const f32x4* __restrict__ sp4 =
            (const f32x4*)(spk1 + (size_t)b * NG * NW);
        f32x4* sk4 = (f32x4*)&sk[0][0];
        #pragma unroll
        for (int i = 0; i < 10; ++i)
            sk4[t + i * 256] = sp4[t + i * 256];
    }
    __syncthreads();

    float2 acc[NG];
    #pragma unroll
    for (int g = 0; g < NG; ++g) { acc[g].x = 0.0f; acc[g].y = 0.0f; }

    int k0 = c * 64;
    #pragma unroll 2
    for (int kkg = 0; kkg < 16; ++kkg) {
        int kk = k0 + kkg * 4;
        float2 a0 = *(const float2*)&wT[(kk + 0) * NH + h];
        float2 a1 = *(const float2*)&wT[(kk + 1) * NH + h];
        float2 a2 = *(const float2*)&wT[(kk + 2) * NH + h];
        float2 a3 = *(const float2*)&wT[(kk + 3) * NH + h];
        #pragma unroll
        for (int g = 0; g < NG; ++g) {
            f32x4 u = *(const f32x4*)&sk[g][kk];   // half-wave-uniform broadcast
            acc[g].x = fmaf(u[0], a0.x, fmaf(u[1], a1.x,
                       fmaf(u[2], a2.x, fmaf(u[3], a3.x, acc[g].x))));
            acc[g].y = fmaf(u[0], a0.y, fmaf(u[1], a1.y,
                       fmaf(u[2], a2.y, fmaf(u[3], a3.y, acc[g].y))));
        }
    }

    // two-phase reduction: chunks 0-3 write; chunks 4-7 accumulate in place
    if (c < 4) {
        #pragma unroll
        for (int g = 0; g < NG; ++g)
            *(float2*)&red[c][g][lane5 * 2] = acc[g];
    }
    __syncthreads();
    if (c >= 4) {
        #pragma unroll
        for (int g = 0; g < NG; ++g) {
            float2 v = *(float2*)&red[c - 4][g][lane5 * 2];
            v.x += acc[g].x; v.y += acc[g].y;
            *(float2*)&red[c - 4][g][lane5 * 2] = v;
        }
    }
    __syncthreads();

    // wave 0: 20-step scan (one h per lane) + folded output layer
    if (t < 64) {
        float hbias = hb[hgrp * 64 + t];
        float mem = 0.0f;
        #pragma unroll
        for (int g = 0; g < NG; ++g) {
            float xin = red[0][g][t] + red[1][g][t]
                      + red[2][g][t] + red[3][g][t] + hbias;
            float base = fmaf(BETA, mem, xin);
            mem = (mem > THRESH) ? 0.0f : base;
        }
        float spike = (mem > THRESH) ? 1.0f : 0.0f;

        // 10 output dots over this block's 64 h, 64-lane shfl reduction
        #pragma unroll
        for (int o = 0; o < NO; ++o) {
            float p = spike * ow[o * NH + hgrp * 64 + t];
            p += __shfl_down(p, 32);
            p += __shfl_down(p, 16);
            p += __shfl_down(p, 8);
            p += __shfl_down(p, 4);
            p += __shfl_down(p, 2);
            p += __shfl_down(p, 1);
            if (t == 0) partial[(b * 16 + hgrp) * NO + o] = p;
        }
    }
}

// ---------------- Kernel 3: micro softmax over summed partials ----------------
__global__ __launch_bounds__(64) void k_softmax(
    const float* __restrict__ partial,  // [B][16][10]
    const float* __restrict__ ob,       // [10]
    float* __restrict__ out)            // [B][10]
{
    int t = threadIdx.x;
    if (t < NB) {
        const float* p = partial + t * 16 * NO;
        float v[NO];
        #pragma unroll
        for (int o = 0; o < NO; ++o) v[o] = ob[o];
        #pragma unroll
        for (int hg = 0; hg < 16; ++hg)
            #pragma unroll
            for (int o = 0; o < NO; ++o) v[o] += p[hg * NO + o];

        float mx = -1e30f;
        #pragma unroll
        for (int o = 0; o < NO; ++o) mx = fmaxf(mx, v[o]);
        float sum = 0.0f;
        #pragma unroll
        for (int o = 0; o < NO; ++o) { v[o] = expf(v[o] - mx); sum += v[o]; }
        float inv = 1.0f / sum;
        #pragma unroll
        for (int o = 0; o < NO; ++o) out[t * NO + o] = v[o] * inv;
    }
}

extern "C" void kernel_launch(void* const* d_in, const int* in_sizes, int n_in,
                              void* d_out, int out_size, void* d_ws, size_t ws_size,
                              hipStream_t stream) {
    const f32x4*  x  = (const f32x4*)d_in[0];   // [32][2000][512][4]
    const float*  cw = (const float*)d_in[1];   // [4]
    const float*  cb = (const float*)d_in[2];   // [1]
    const float*  hw = (const float*)d_in[3];   // [1024][512]
    const float*  hb = (const float*)d_in[4];   // [1024]
    const float*  ow = (const float*)d_in[5];   // [10][1024]
    const float*  ob = (const float*)d_in[6];   // [10]
    float* out = (float*)d_out;                 // [32][10]

    char* ws = (char*)d_ws;
    float* spk1    = (float*)(ws);                        // 32*20*512*4 = 1,310,720 B
    float* wT      = (float*)(ws + 1310720);              // 512*1024*4  = 2,097,152 B
    float* partial = (float*)(ws + 1310720 + 2097152);    // 32*16*10*4  =    20,480 B

    // stage 1: conv + scan1 (~78us, HBM roofline) fused with weight transpose
    k1_conv_scan_tr<<<1792, 256, 0, stream>>>(x, cw, cb, spk1, hw, wT);

    // stage 2+3+4a: hidden GEMM (2 blocks/CU) + scan2 + output partial dots
    k2_hidden_scan<<<NB * 16, 256, 0, stream>>>(spk1, wT, hb, ow, partial);

    // stage 4b: sum partials + bias + softmax (1 tiny block)
    k_softmax<<<1, 64, 0, stream>>>(partial, ob, out);
}